// Round 2
// baseline (6818.118 us; speedup 1.0000x reference)
//
#include <hip/hip_runtime.h>
#include <hip/hip_bf16.h>

// Problem constants (from reference)
#define B_  2
#define T_  2048
#define D_  2048
#define H_  16
#define KV_ 4
#define HD_ 128
#define BT_ (B_*T_)          // 4096 token rows
static constexpr float EPS_ = 1e-6f;

// ---------------------------------------------------------------------------
// Generic GEMM: C[M,N] = A[M,K] @ W[K,N], f32 in, f32 accumulate, f32 out.
// 64x64 tile, BK=16, 256 threads (16x16), 4x4 micro-tile per thread.
// Correctness-first baseline; MFMA comes in a later round.
// ---------------------------------------------------------------------------
#define BM 64
#define BN 64
#define BK 16
__global__ __launch_bounds__(256) void gemm_f32_kernel(
    const float* __restrict__ A, const float* __restrict__ W,
    float* __restrict__ C, int M, int N, int K)
{
    __shared__ float As[BM][BK+1];   // +1 pad breaks bank conflicts on column reads
    __shared__ float Bs[BK][BN];
    const int tx = threadIdx.x, ty = threadIdx.y;     // 16x16
    const int tid = ty*16 + tx;
    const int row0 = blockIdx.y*BM, col0 = blockIdx.x*BN;

    float acc[4][4] = {};
    for (int k0 = 0; k0 < K; k0 += BK) {
        // stage A tile (BM x BK = 1024 elems, 4/thread)
        #pragma unroll
        for (int i = 0; i < 4; i++) {
            int e = tid*4 + i;
            int r = e / BK, c = e % BK;
            As[r][c] = A[(size_t)(row0 + r)*K + k0 + c];
        }
        // stage W tile (BK x BN = 1024 elems, 4/thread)
        #pragma unroll
        for (int i = 0; i < 4; i++) {
            int e = tid*4 + i;
            int r = e / BN, c = e % BN;
            Bs[r][c] = W[(size_t)(k0 + r)*N + col0 + c];
        }
        __syncthreads();
        #pragma unroll
        for (int kk = 0; kk < BK; kk++) {
            float a[4], b[4];
            #pragma unroll
            for (int i = 0; i < 4; i++) a[i] = As[ty*4 + i][kk];
            #pragma unroll
            for (int j = 0; j < 4; j++) b[j] = Bs[kk][tx + j*16];
            #pragma unroll
            for (int i = 0; i < 4; i++)
                #pragma unroll
                for (int j = 0; j < 4; j++)
                    acc[i][j] += a[i]*b[j];
        }
        __syncthreads();
    }
    #pragma unroll
    for (int i = 0; i < 4; i++)
        #pragma unroll
        for (int j = 0; j < 4; j++)
            C[(size_t)(row0 + ty*4 + i)*N + col0 + tx + j*16] = acc[i][j];
}

// ---------------------------------------------------------------------------
// Fused RMSNorm (over HD) + RoPE (interleaved-pair), in place on f32 rows.
// One 128-thread block per head-vector row. heads_per_token = H (q) or KV (k).
// ---------------------------------------------------------------------------
__global__ __launch_bounds__(128) void rmsnorm_rope_kernel(
    float* __restrict__ qk, const float* __restrict__ scale,
    const float* __restrict__ cosT, const float* __restrict__ sinT,
    int heads_per_token)
{
    const int row = blockIdx.x;                    // (b*T + t)*heads + h
    const int d   = threadIdx.x;                   // 0..127
    const int t   = (row / heads_per_token) % T_;
    float* p = qk + (size_t)row * HD_;

    float v = p[d];

    __shared__ float red[HD_];
    __shared__ float xs[HD_];
    red[d] = v*v;
    __syncthreads();
    #pragma unroll
    for (int s = 64; s > 0; s >>= 1) {
        if (d < s) red[d] += red[d + s];
        __syncthreads();
    }
    const float rms = rsqrtf(red[0] * (1.0f/HD_) + EPS_);
    const float xn  = v * rms * scale[d];
    xs[d] = xn;
    __syncthreads();
    const float part = xs[d ^ 1];
    const float rot  = (d & 1) ? part : -part;     // even: -x[d+1]; odd: +x[d-1]
    const float c  = cosT[(size_t)t*HD_ + d];
    const float sn = sinT[(size_t)t*HD_ + d];
    p[d] = xn*c + rot*sn;
}

// ---------------------------------------------------------------------------
// Causal GQA attention, one block per (b, h, q-row). Score row in LDS (8 KB),
// two-pass softmax, then 128 threads accumulate P@V along keys.
// O may alias Q (in-place): each block reads only its own Q row (staged to
// LDS before any write) and writes only that same row.
// ---------------------------------------------------------------------------
__global__ __launch_bounds__(256) void attention_kernel(
    const float* __restrict__ Q, const float* __restrict__ Kk,
    const float* __restrict__ V, float* __restrict__ O)
{
    const int qi  = blockIdx.x;
    const int h   = blockIdx.y;
    const int b   = blockIdx.z;
    const int tid = threadIdx.x;                   // 0..255
    const int kvh = h / (H_/KV_);

    __shared__ float qv[HD_];
    __shared__ float sc[T_];
    __shared__ float red[256];

    const float* qp = Q + ((size_t)(b*T_ + qi)*H_ + h)*HD_;
    if (tid < HD_) qv[tid] = qp[tid];
    __syncthreads();

    const int nk = qi + 1;
    const float scale = 0.08838834764831845f;      // 1/sqrt(128)

    float lmax = -INFINITY;
    for (int k = tid; k < nk; k += 256) {
        const float* kp = Kk + ((size_t)(b*T_ + k)*KV_ + kvh)*HD_;
        float dot = 0.f;
        #pragma unroll 8
        for (int d = 0; d < HD_; d++) dot += qv[d]*kp[d];
        dot *= scale;
        sc[k] = dot;
        lmax = fmaxf(lmax, dot);
    }
    red[tid] = lmax;
    __syncthreads();
    #pragma unroll
    for (int s = 128; s > 0; s >>= 1) {
        if (tid < s) red[tid] = fmaxf(red[tid], red[tid + s]);
        __syncthreads();
    }
    const float m = red[0];
    __syncthreads();

    float lsum = 0.f;
    for (int k = tid; k < nk; k += 256) {
        float p = __expf(sc[k] - m);
        sc[k] = p;
        lsum += p;
    }
    red[tid] = lsum;
    __syncthreads();
    #pragma unroll
    for (int s = 128; s > 0; s >>= 1) {
        if (tid < s) red[tid] += red[tid + s];
        __syncthreads();
    }
    const float inv = 1.0f / red[0];
    __syncthreads();

    if (tid < HD_) {
        float acc = 0.f;
        const float* vbase = V + ((size_t)b*T_*KV_ + kvh)*HD_ + tid;
        for (int k = 0; k < nk; k++) {
            acc += sc[k] * vbase[(size_t)k*KV_*HD_];
        }
        O[((size_t)(b*T_ + qi)*H_ + h)*HD_ + tid] = acc * inv;
    }
}

// ---------------------------------------------------------------------------
extern "C" void kernel_launch(void* const* d_in, const int* in_sizes, int n_in,
                              void* d_out, int out_size, void* d_ws, size_t ws_size,
                              hipStream_t stream)
{
    const float* x    = (const float*)d_in[0];   // [B,T,D]
    const float* Wq   = (const float*)d_in[1];   // [D, H*HD]
    const float* Wk   = (const float*)d_in[2];   // [D, KV*HD]
    const float* Wv   = (const float*)d_in[3];   // [D, KV*HD]
    const float* Wo   = (const float*)d_in[4];   // [H*HD, D]
    const float* qsc  = (const float*)d_in[5];   // [HD]
    const float* ksc  = (const float*)d_in[6];   // [HD]
    const float* cosT = (const float*)d_in[7];   // [T, HD]
    const float* sinT = (const float*)d_in[8];   // [T, HD]
    // d_in[9] = causal mask — hard-coded, unused.
    float* out = (float*)d_out;

    // Workspace carve (f32): q_lin 33.5 MB, k_lin 8.4 MB, v_lin 8.4 MB = ~50 MB.
    // Attention output written in-place into q_lin (safe — see kernel comment).
    float* q_lin = (float*)d_ws;
    float* k_lin = q_lin + (size_t)BT_*H_*HD_;
    float* v_lin = k_lin + (size_t)BT_*KV_*HD_;

    dim3 tgemm(16, 16);
    // q = x @ Wq  : [4096,2048] x [2048,2048]
    gemm_f32_kernel<<<dim3((H_*HD_)/BN, BT_/BM), tgemm, 0, stream>>>(
        x, Wq, q_lin, BT_, H_*HD_, D_);
    // k = x @ Wk  : [4096,2048] x [2048,512]
    gemm_f32_kernel<<<dim3((KV_*HD_)/BN, BT_/BM), tgemm, 0, stream>>>(
        x, Wk, k_lin, BT_, KV_*HD_, D_);
    // v = x @ Wv
    gemm_f32_kernel<<<dim3((KV_*HD_)/BN, BT_/BM), tgemm, 0, stream>>>(
        x, Wv, v_lin, BT_, KV_*HD_, D_);

    // RMSNorm + RoPE in place
    rmsnorm_rope_kernel<<<BT_*H_,  HD_, 0, stream>>>(q_lin, qsc, cosT, sinT, H_);
    rmsnorm_rope_kernel<<<BT_*KV_, HD_, 0, stream>>>(k_lin, ksc, cosT, sinT, KV_);

    // Attention (output in-place into q_lin)
    attention_kernel<<<dim3(T_, H_, B_), 256, 0, stream>>>(q_lin, k_lin, v_lin, q_lin);

    // out = attn @ Wo : [4096,2048] x [2048,2048]
    gemm_f32_kernel<<<dim3(D_/BN, BT_/BM), tgemm, 0, stream>>>(
        q_lin, Wo, out, BT_, D_, D_);
}

// Round 3
// 2197.482 us; speedup vs baseline: 3.1027x; 3.1027x over previous
//
#include <hip/hip_runtime.h>
#include <hip/hip_bf16.h>

// Problem constants (from reference)
#define B_  2
#define T_  2048
#define D_  2048
#define H_  16
#define KV_ 4
#define HD_ 128
#define BT_ (B_*T_)          // 4096 token rows
static constexpr float EPS_ = 1e-6f;

typedef __attribute__((ext_vector_type(8))) short short8;   // 8 bf16 = 4 VGPR
typedef __attribute__((ext_vector_type(4))) float f32x4;    // MFMA acc

__device__ __forceinline__ unsigned short f2bf(float f){
    unsigned u = __float_as_uint(f);
    u += 0x7FFF + ((u >> 16) & 1);          // round-to-nearest-even
    return (unsigned short)(u >> 16);
}

// ---------------------------------------------------------------------------
// Generic GEMM: C[M,N] = A[M,K] @ W[K,N], f32. Known-correct baseline (round 2).
// ---------------------------------------------------------------------------
#define BM 64
#define BN 64
#define BK 16
__global__ __launch_bounds__(256) void gemm_f32_kernel(
    const float* __restrict__ A, const float* __restrict__ W,
    float* __restrict__ C, int M, int N, int K)
{
    __shared__ float As[BM][BK+1];
    __shared__ float Bs[BK][BN];
    const int tx = threadIdx.x, ty = threadIdx.y;
    const int tid = ty*16 + tx;
    const int row0 = blockIdx.y*BM, col0 = blockIdx.x*BN;

    float acc[4][4] = {};
    for (int k0 = 0; k0 < K; k0 += BK) {
        #pragma unroll
        for (int i = 0; i < 4; i++) {
            int e = tid*4 + i;
            int r = e / BK, c = e % BK;
            As[r][c] = A[(size_t)(row0 + r)*K + k0 + c];
        }
        #pragma unroll
        for (int i = 0; i < 4; i++) {
            int e = tid*4 + i;
            int r = e / BN, c = e % BN;
            Bs[r][c] = W[(size_t)(k0 + r)*N + col0 + c];
        }
        __syncthreads();
        #pragma unroll
        for (int kk = 0; kk < BK; kk++) {
            float a[4], b[4];
            #pragma unroll
            for (int i = 0; i < 4; i++) a[i] = As[ty*4 + i][kk];
            #pragma unroll
            for (int j = 0; j < 4; j++) b[j] = Bs[kk][tx + j*16];
            #pragma unroll
            for (int i = 0; i < 4; i++)
                #pragma unroll
                for (int j = 0; j < 4; j++)
                    acc[i][j] += a[i]*b[j];
        }
        __syncthreads();
    }
    #pragma unroll
    for (int i = 0; i < 4; i++)
        #pragma unroll
        for (int j = 0; j < 4; j++)
            C[(size_t)(row0 + ty*4 + i)*N + col0 + tx + j*16] = acc[i][j];
}

// ---------------------------------------------------------------------------
// Fused RMSNorm + RoPE, in place on f32 rows (unchanged from round 2).
// ---------------------------------------------------------------------------
__global__ __launch_bounds__(128) void rmsnorm_rope_kernel(
    float* __restrict__ qk, const float* __restrict__ scale,
    const float* __restrict__ cosT, const float* __restrict__ sinT,
    int heads_per_token)
{
    const int row = blockIdx.x;
    const int d   = threadIdx.x;
    const int t   = (row / heads_per_token) % T_;
    float* p = qk + (size_t)row * HD_;

    float v = p[d];
    __shared__ float red[HD_];
    __shared__ float xs[HD_];
    red[d] = v*v;
    __syncthreads();
    #pragma unroll
    for (int s = 64; s > 0; s >>= 1) {
        if (d < s) red[d] += red[d + s];
        __syncthreads();
    }
    const float rms = rsqrtf(red[0] * (1.0f/HD_) + EPS_);
    const float xn  = v * rms * scale[d];
    xs[d] = xn;
    __syncthreads();
    const float part = xs[d ^ 1];
    const float rot  = (d & 1) ? part : -part;
    p[d] = xn*cosT[(size_t)t*HD_ + d] + rot*sinT[(size_t)t*HD_ + d];
}

// ---------------------------------------------------------------------------
// Flash-style causal GQA attention with MFMA (bf16 compute, f32 softmax/acc).
// Block = 256 threads (4 waves) handles (b, h, 64 q-rows); iterates 32-key
// tiles. Verified gfx950 16x16x32 bf16 fragment layouts:
//   A: [m=lane&15][k=quad*8+j]  B: [n=lane&15][k=quad*8+j]
//   C/D: col=lane&15, row=quad*4+reg
// O may alias Q (each block reads only its own Q rows, staged before write).
// ---------------------------------------------------------------------------
#define BQ  64
#define BKV 32
#define SQF 136   // Qs/Ks stride, bf16 elems, %8==0 (16B-aligned frag reads)
#define SVP 40    // Vt/Pb stride
#define SSF 33    // Sf stride (f32)

__global__ __launch_bounds__(256) void attn_mfma_kernel(
    const float* __restrict__ Qg, const float* __restrict__ Kg,
    const float* __restrict__ Vg, float* __restrict__ Og)
{
    __shared__ __align__(16) unsigned short Qs[BQ][SQF];
    __shared__ __align__(16) unsigned short Ks[BKV][SQF];
    __shared__ __align__(16) unsigned short Vt[HD_][SVP];   // V transposed [d][k]
    __shared__ __align__(16) unsigned short Pb[BQ][SVP];
    __shared__ float Sf[BQ][SSF];
    __shared__ float alphas[BQ];
    __shared__ float lrow[BQ];

    const int qt   = (gridDim.x - 1) - blockIdx.x;   // heavy (long-causal) first
    const int h    = blockIdx.y;
    const int b    = blockIdx.z;
    const int q0   = qt * BQ;
    const int kvh  = h / (H_/KV_);
    const int tid  = threadIdx.x;
    const int lane = tid & 63;
    const int wave = tid >> 6;
    const int l15  = lane & 15;
    const int quad = lane >> 4;
    const float SCALE = 0.08838834764831845f;        // 1/sqrt(128)

    // ---- stage Q tile once: 64 rows x 128, f32 -> bf16 ----
    {
        const int r  = tid >> 2;
        const int c0 = (tid & 3) * 32;
        const float* qrow = Qg + ((size_t)(b*T_ + q0 + r)*H_ + h)*HD_ + c0;
        unsigned short* dst = &Qs[r][c0];
        #pragma unroll
        for (int i = 0; i < 8; i++) {
            float4 v = *(const float4*)(qrow + i*4);
            dst[i*4+0] = f2bf(v.x); dst[i*4+1] = f2bf(v.y);
            dst[i*4+2] = f2bf(v.z); dst[i*4+3] = f2bf(v.w);
        }
    }

    float m_r = -INFINITY, l_r = 0.0f;               // softmax state (tid<64)
    f32x4 oacc[8];                                    // O: row-tile=wave, 8 col-tiles
    #pragma unroll
    for (int cv = 0; cv < 8; cv++) oacc[cv] = (f32x4){0.f,0.f,0.f,0.f};

    const int ntiles = (q0 + BQ + BKV - 1) / BKV;
    for (int t = 0; t < ntiles; t++) {
        const int k0 = t * BKV;
        __syncthreads();                              // prev PV done before restage

        // ---- stage K tile (32 x 128) row-major bf16 ----
        {
            const int r  = tid >> 3;
            const int c0 = (tid & 7) * 16;
            const float* krow = Kg + ((size_t)(b*T_ + k0 + r)*KV_ + kvh)*HD_ + c0;
            unsigned short* kd = &Ks[r][c0];
            #pragma unroll
            for (int i = 0; i < 4; i++) {
                float4 v = *(const float4*)(krow + i*4);
                kd[i*4+0] = f2bf(v.x); kd[i*4+1] = f2bf(v.y);
                kd[i*4+2] = f2bf(v.z); kd[i*4+3] = f2bf(v.w);
            }
        }
        // ---- stage V tile transposed: Vt[d][k] ----
        {
            const int r = tid >> 3;                  // key row
            const float* vrow = Vg + ((size_t)(b*T_ + k0 + r)*KV_ + kvh)*HD_;
            #pragma unroll
            for (int p = 0; p < 4; p++) {
                const int c = p*32 + (tid & 7)*4;
                float4 v = *(const float4*)(vrow + c);
                Vt[c+0][r] = f2bf(v.x); Vt[c+1][r] = f2bf(v.y);
                Vt[c+2][r] = f2bf(v.z); Vt[c+3][r] = f2bf(v.w);
            }
        }
        __syncthreads();

        // ---- S = Q @ K^T  (wave -> 16-row slab, 2 col-tiles of 16 keys) ----
        {
            f32x4 sacc[2];
            sacc[0] = (f32x4){0.f,0.f,0.f,0.f};
            sacc[1] = (f32x4){0.f,0.f,0.f,0.f};
            #pragma unroll
            for (int kt = 0; kt < 4; kt++) {
                short8 af = *(const short8*)&Qs[wave*16 + l15][kt*32 + quad*8];
                #pragma unroll
                for (int c = 0; c < 2; c++) {
                    short8 bf = *(const short8*)&Ks[c*16 + l15][kt*32 + quad*8];
                    sacc[c] = __builtin_amdgcn_mfma_f32_16x16x32_bf16(af, bf, sacc[c], 0, 0, 0);
                }
            }
            #pragma unroll
            for (int c = 0; c < 2; c++)
                #pragma unroll
                for (int r = 0; r < 4; r++)
                    Sf[wave*16 + quad*4 + r][c*16 + l15] = sacc[c][r] * SCALE;
        }
        __syncthreads();

        // ---- online softmax: thread r (tid<64) owns q-row r ----
        if (tid < BQ) {
            const int r = tid;
            int kvalid = q0 + r - k0 + 1;
            if (kvalid > BKV) kvalid = BKV;
            float alpha = 1.0f;
            if (kvalid > 0) {
                float mloc = -INFINITY;
                for (int j = 0; j < kvalid; j++) mloc = fmaxf(mloc, Sf[r][j]);
                const float mnew = fmaxf(m_r, mloc);
                alpha = __expf(m_r - mnew);           // m_r=-inf -> 0
                m_r = mnew;
                float lad = 0.0f;
                for (int j = 0; j < BKV; j++) {
                    float p = (j < kvalid) ? __expf(Sf[r][j] - mnew) : 0.0f;
                    lad += p;
                    Pb[r][j] = f2bf(p);
                }
                l_r = alpha * l_r + lad;
            } else {
                for (int j = 0; j < BKV; j++) Pb[r][j] = 0;
            }
            alphas[r] = alpha;
            lrow[r]   = l_r;
        }
        __syncthreads();

        // ---- O = alpha*O + P @ V ----
        {
            float av0 = alphas[wave*16 + quad*4 + 0];
            float av1 = alphas[wave*16 + quad*4 + 1];
            float av2 = alphas[wave*16 + quad*4 + 2];
            float av3 = alphas[wave*16 + quad*4 + 3];
            short8 pf = *(const short8*)&Pb[wave*16 + l15][quad*8];
            #pragma unroll
            for (int cv = 0; cv < 8; cv++) {
                oacc[cv][0] *= av0; oacc[cv][1] *= av1;
                oacc[cv][2] *= av2; oacc[cv][3] *= av3;
                short8 vf = *(const short8*)&Vt[cv*16 + l15][quad*8];
                oacc[cv] = __builtin_amdgcn_mfma_f32_16x16x32_bf16(pf, vf, oacc[cv], 0, 0, 0);
            }
        }
    }

    // ---- epilogue: O / l -> global (in-place into Q buffer is safe) ----
    __syncthreads();
    #pragma unroll
    for (int r = 0; r < 4; r++) {
        const int row = wave*16 + quad*4 + r;
        const float linv = 1.0f / lrow[row];
        float* orow = Og + ((size_t)(b*T_ + q0 + row)*H_ + h)*HD_ + l15;
        #pragma unroll
        for (int cv = 0; cv < 8; cv++)
            orow[cv*16] = oacc[cv][r] * linv;
    }
}

// ---------------------------------------------------------------------------
extern "C" void kernel_launch(void* const* d_in, const int* in_sizes, int n_in,
                              void* d_out, int out_size, void* d_ws, size_t ws_size,
                              hipStream_t stream)
{
    const float* x    = (const float*)d_in[0];   // [B,T,D]
    const float* Wq   = (const float*)d_in[1];   // [D, H*HD]
    const float* Wk   = (const float*)d_in[2];   // [D, KV*HD]
    const float* Wv   = (const float*)d_in[3];   // [D, KV*HD]
    const float* Wo   = (const float*)d_in[4];   // [H*HD, D]
    const float* qsc  = (const float*)d_in[5];   // [HD]
    const float* ksc  = (const float*)d_in[6];   // [HD]
    const float* cosT = (const float*)d_in[7];   // [T, HD]
    const float* sinT = (const float*)d_in[8];   // [T, HD]
    float* out = (float*)d_out;

    float* q_lin = (float*)d_ws;
    float* k_lin = q_lin + (size_t)BT_*H_*HD_;
    float* v_lin = k_lin + (size_t)BT_*KV_*HD_;

    dim3 tgemm(16, 16);
    gemm_f32_kernel<<<dim3((H_*HD_)/BN, BT_/BM), tgemm, 0, stream>>>(
        x, Wq, q_lin, BT_, H_*HD_, D_);
    gemm_f32_kernel<<<dim3((KV_*HD_)/BN, BT_/BM), tgemm, 0, stream>>>(
        x, Wk, k_lin, BT_, KV_*HD_, D_);
    gemm_f32_kernel<<<dim3((KV_*HD_)/BN, BT_/BM), tgemm, 0, stream>>>(
        x, Wv, v_lin, BT_, KV_*HD_, D_);

    rmsnorm_rope_kernel<<<BT_*H_,  HD_, 0, stream>>>(q_lin, qsc, cosT, sinT, H_);
    rmsnorm_rope_kernel<<<BT_*KV_, HD_, 0, stream>>>(k_lin, ksc, cosT, sinT, KV_);

    // Flash attention (output in-place into q_lin)
    attn_mfma_kernel<<<dim3(T_/BQ, H_, B_), 256, 0, stream>>>(
        q_lin, k_lin, v_lin, q_lin);

    // out = attn @ Wo
    gemm_f32_kernel<<<dim3(D_/BN, BT_/BM), tgemm, 0, stream>>>(
        q_lin, Wo, out, BT_, D_, D_);
}

// Round 4
// 967.934 us; speedup vs baseline: 7.0440x; 2.2703x over previous
//
#include <hip/hip_runtime.h>
#include <hip/hip_bf16.h>

// Problem constants (from reference)
#define B_  2
#define T_  2048
#define D_  2048
#define H_  16
#define KV_ 4
#define HD_ 128
#define BT_ (B_*T_)          // 4096 token rows
static constexpr float EPS_ = 1e-6f;

typedef unsigned short u16;
typedef __attribute__((ext_vector_type(8))) short short8;          // 8 bf16 = 16 B
typedef __attribute__((ext_vector_type(4))) float f32x4;           // MFMA acc
typedef __attribute__((ext_vector_type(4))) unsigned short u16x4;  // 8 B

__device__ __forceinline__ u16 f2bf(float f){
    unsigned u = __float_as_uint(f);
    u += 0x7FFF + ((u >> 16) & 1);          // round-to-nearest-even
    return (u16)(u >> 16);
}
__device__ __forceinline__ float bf2f(u16 u){
    return __uint_as_float((unsigned)u << 16);
}

// Async global->LDS, 16 B per lane. LDS dest must be wave-uniform base + lane*16.
__device__ __forceinline__ void async_copy16(const void* g, void* l) {
    __builtin_amdgcn_global_load_lds(
        (const __attribute__((address_space(1))) unsigned int*)g,
        (__attribute__((address_space(3))) unsigned int*)l, 16, 0, 0);
}

// ---------------------------------------------------------------------------
// f32 -> bf16 elementwise convert (n % 4 == 0)
// ---------------------------------------------------------------------------
__global__ __launch_bounds__(256) void cvt_f32_bf16_kernel(
    const float* __restrict__ in, u16* __restrict__ out, int n)
{
    const int i = (blockIdx.x*256 + threadIdx.x)*4;
    if (i < n) {
        float4 v = *(const float4*)&in[i];
        u16x4 w = { f2bf(v.x), f2bf(v.y), f2bf(v.z), f2bf(v.w) };
        *(u16x4*)&out[i] = w;
    }
}

// ---------------------------------------------------------------------------
// Transpose + convert: in [R][C] f32  ->  out [C][R] bf16.  64x64 LDS tile.
// ---------------------------------------------------------------------------
__global__ __launch_bounds__(256) void transpose_cvt_kernel(
    const float* __restrict__ in, u16* __restrict__ out, int R, int C)
{
    __shared__ u16 tile[64][65];
    const int r0 = blockIdx.y*64, c0 = blockIdx.x*64;
    const int tr = threadIdx.x >> 4;          // 0..15
    const int tc = (threadIdx.x & 15) * 4;    // 0,4,..60
    #pragma unroll
    for (int i = 0; i < 4; i++) {
        const int r = tr + i*16;
        float4 v = *(const float4*)&in[(size_t)(r0 + r)*C + c0 + tc];
        tile[tc+0][r] = f2bf(v.x);
        tile[tc+1][r] = f2bf(v.y);
        tile[tc+2][r] = f2bf(v.z);
        tile[tc+3][r] = f2bf(v.w);
    }
    __syncthreads();
    #pragma unroll
    for (int i = 0; i < 4; i++) {
        const int c = tr + i*16;
        u16x4 w = { tile[c][tc+0], tile[c][tc+1], tile[c][tc+2], tile[c][tc+3] };
        *(u16x4*)&out[(size_t)(c0 + c)*R + r0 + tc] = w;
    }
}

// ---------------------------------------------------------------------------
// m97-style MFMA GEMM: C[M,N] = A[M,K] @ Bt[N,K]^T, bf16 in, f32 acc.
// 128x128 tile, BK=32, 256 threads (4 waves, 2x2 quadrants of 64x64,
// each wave 4x4 MFMA 16x16x32 tiles). global_load_lds width-16 staging.
// Fragment layouts verified via the round-2/3 attention kernel:
//   A/B: [idx=lane&15][k=quad*8+j]   C/D: col=lane&15, row=quad*4+reg
// ---------------------------------------------------------------------------
#define GBM 128
#define GBN 128
#define GBK 32

template<bool OUT_BF16>
__global__ __launch_bounds__(256) void gemm_mfma_kernel(
    const u16* __restrict__ A, const u16* __restrict__ Bt,
    void* __restrict__ C, int M, int N, int K)
{
    __shared__ __align__(16) u16 As[GBM][GBK];   // 8 KB, unpadded (global_load_lds)
    __shared__ __align__(16) u16 Bs[GBN][GBK];   // 8 KB
    const int tid  = threadIdx.x;
    const int lane = tid & 63;
    const int wave = tid >> 6;
    const int l15  = lane & 15;
    const int quad = lane >> 4;
    const int wr   = (wave >> 1) * 64;           // wave quadrant row
    const int wc   = (wave & 1) * 64;            // wave quadrant col
    const size_t row0 = (size_t)blockIdx.y * GBM;
    const size_t col0 = (size_t)blockIdx.x * GBN;

    f32x4 acc[4][4];
    #pragma unroll
    for (int i = 0; i < 4; i++)
        #pragma unroll
        for (int j = 0; j < 4; j++)
            acc[i][j] = (f32x4){0.f,0.f,0.f,0.f};

    for (int k0 = 0; k0 < K; k0 += GBK) {
        #pragma unroll
        for (int c = 0; c < 2; c++) {
            const int e = (c*256 + tid) * 8;     // bf16 elem offset in 128x32 tile
            const int r = e >> 5, cc = e & 31;
            async_copy16(A  + (row0 + r)*K + k0 + cc, &As[r][cc]);
            async_copy16(Bt + (col0 + r)*K + k0 + cc, &Bs[r][cc]);
        }
        __syncthreads();                          // drains vmcnt before use

        short8 af[4], bf[4];
        #pragma unroll
        for (int i = 0; i < 4; i++)
            af[i] = *(const short8*)&As[wr + i*16 + l15][quad*8];
        #pragma unroll
        for (int j = 0; j < 4; j++)
            bf[j] = *(const short8*)&Bs[wc + j*16 + l15][quad*8];
        #pragma unroll
        for (int i = 0; i < 4; i++)
            #pragma unroll
            for (int j = 0; j < 4; j++)
                acc[i][j] = __builtin_amdgcn_mfma_f32_16x16x32_bf16(
                    af[i], bf[j], acc[i][j], 0, 0, 0);
        __syncthreads();
    }

    #pragma unroll
    for (int i = 0; i < 4; i++)
        #pragma unroll
        for (int r = 0; r < 4; r++) {
            const size_t row = row0 + wr + i*16 + quad*4 + r;
            #pragma unroll
            for (int j = 0; j < 4; j++) {
                const size_t col = col0 + wc + j*16 + l15;
                if (OUT_BF16) ((u16*)C)[row*N + col] = f2bf(acc[i][j][r]);
                else          ((float*)C)[row*N + col] = acc[i][j][r];
            }
        }
}

// ---------------------------------------------------------------------------
// Fused RMSNorm + RoPE, in place on bf16 rows.
// ---------------------------------------------------------------------------
__global__ __launch_bounds__(128) void rmsnorm_rope_kernel(
    u16* __restrict__ qk, const float* __restrict__ scale,
    const float* __restrict__ cosT, const float* __restrict__ sinT,
    int heads_per_token)
{
    const int row = blockIdx.x;
    const int d   = threadIdx.x;
    const int t   = (row / heads_per_token) % T_;
    u16* p = qk + (size_t)row * HD_;

    float v = bf2f(p[d]);
    __shared__ float red[HD_];
    __shared__ float xs[HD_];
    red[d] = v*v;
    __syncthreads();
    #pragma unroll
    for (int s = 64; s > 0; s >>= 1) {
        if (d < s) red[d] += red[d + s];
        __syncthreads();
    }
    const float rms = rsqrtf(red[0] * (1.0f/HD_) + EPS_);
    const float xn  = v * rms * scale[d];
    xs[d] = xn;
    __syncthreads();
    const float part = xs[d ^ 1];
    const float rot  = (d & 1) ? part : -part;
    p[d] = f2bf(xn*cosT[(size_t)t*HD_ + d] + rot*sinT[(size_t)t*HD_ + d]);
}

// ---------------------------------------------------------------------------
// Flash-style causal GQA attention with MFMA — bf16 in/out (round-3 logic).
// O may alias Q (each block reads only its own Q rows, staged before write).
// ---------------------------------------------------------------------------
#define BQ  64
#define BKV 32
#define SQF 136   // Qs/Ks stride, bf16 elems (16B-aligned frag reads)
#define SVP 40    // Vt/Pb stride
#define SSF 33    // Sf stride (f32)

__global__ __launch_bounds__(256) void attn_mfma_kernel(
    const u16* __restrict__ Qg, const u16* __restrict__ Kg,
    const u16* __restrict__ Vg, u16* __restrict__ Og)
{
    __shared__ __align__(16) u16 Qs[BQ][SQF];
    __shared__ __align__(16) u16 Ks[BKV][SQF];
    __shared__ __align__(16) u16 Vt[HD_][SVP];   // V transposed [d][k]
    __shared__ __align__(16) u16 Pb[BQ][SVP];
    __shared__ float Sf[BQ][SSF];
    __shared__ float alphas[BQ];
    __shared__ float lrow[BQ];

    const int qt   = (gridDim.x - 1) - blockIdx.x;   // heavy (long-causal) first
    const int h    = blockIdx.y;
    const int b    = blockIdx.z;
    const int q0   = qt * BQ;
    const int kvh  = h / (H_/KV_);
    const int tid  = threadIdx.x;
    const int lane = tid & 63;
    const int wave = tid >> 6;
    const int l15  = lane & 15;
    const int quad = lane >> 4;
    const float SCALE = 0.08838834764831845f;        // 1/sqrt(128)

    // ---- stage Q tile once: 64 rows x 128 bf16 ----
    {
        const int r  = tid >> 2;
        const int c0 = (tid & 3) * 32;
        const u16* qrow = Qg + ((size_t)(b*T_ + q0 + r)*H_ + h)*HD_ + c0;
        #pragma unroll
        for (int i = 0; i < 4; i++)
            *(short8*)&Qs[r][c0 + i*8] = *(const short8*)(qrow + i*8);
    }

    float m_r = -INFINITY, l_r = 0.0f;               // softmax state (tid<64)
    f32x4 oacc[8];
    #pragma unroll
    for (int cv = 0; cv < 8; cv++) oacc[cv] = (f32x4){0.f,0.f,0.f,0.f};

    const int ntiles = (q0 + BQ + BKV - 1) / BKV;
    for (int t = 0; t < ntiles; t++) {
        const int k0 = t * BKV;
        __syncthreads();                              // prev PV done before restage

        // ---- stage K tile (32 x 128) bf16 ----
        {
            const int r  = tid >> 3;
            const int c0 = (tid & 7) * 16;
            const u16* krow = Kg + ((size_t)(b*T_ + k0 + r)*KV_ + kvh)*HD_ + c0;
            *(short8*)&Ks[r][c0]     = *(const short8*)(krow);
            *(short8*)&Ks[r][c0 + 8] = *(const short8*)(krow + 8);
        }
        // ---- stage V tile transposed: Vt[d][k] ----
        {
            const int r = tid >> 3;
            const u16* vrow = Vg + ((size_t)(b*T_ + k0 + r)*KV_ + kvh)*HD_;
            #pragma unroll
            for (int p = 0; p < 4; p++) {
                const int c = p*32 + (tid & 7)*4;
                u16x4 v = *(const u16x4*)(vrow + c);
                Vt[c+0][r] = v[0]; Vt[c+1][r] = v[1];
                Vt[c+2][r] = v[2]; Vt[c+3][r] = v[3];
            }
        }
        __syncthreads();

        // ---- S = Q @ K^T ----
        {
            f32x4 sacc[2];
            sacc[0] = (f32x4){0.f,0.f,0.f,0.f};
            sacc[1] = (f32x4){0.f,0.f,0.f,0.f};
            #pragma unroll
            for (int kt = 0; kt < 4; kt++) {
                short8 af = *(const short8*)&Qs[wave*16 + l15][kt*32 + quad*8];
                #pragma unroll
                for (int c = 0; c < 2; c++) {
                    short8 bf = *(const short8*)&Ks[c*16 + l15][kt*32 + quad*8];
                    sacc[c] = __builtin_amdgcn_mfma_f32_16x16x32_bf16(af, bf, sacc[c], 0, 0, 0);
                }
            }
            #pragma unroll
            for (int c = 0; c < 2; c++)
                #pragma unroll
                for (int r = 0; r < 4; r++)
                    Sf[wave*16 + quad*4 + r][c*16 + l15] = sacc[c][r] * SCALE;
        }
        __syncthreads();

        // ---- online softmax: thread r (tid<64) owns q-row r ----
        if (tid < BQ) {
            const int r = tid;
            int kvalid = q0 + r - k0 + 1;
            if (kvalid > BKV) kvalid = BKV;
            float alpha = 1.0f;
            if (kvalid > 0) {
                float mloc = -INFINITY;
                for (int j = 0; j < kvalid; j++) mloc = fmaxf(mloc, Sf[r][j]);
                const float mnew = fmaxf(m_r, mloc);
                alpha = __expf(m_r - mnew);
                m_r = mnew;
                float lad = 0.0f;
                for (int j = 0; j < BKV; j++) {
                    float p = (j < kvalid) ? __expf(Sf[r][j] - mnew) : 0.0f;
                    lad += p;
                    Pb[r][j] = f2bf(p);
                }
                l_r = alpha * l_r + lad;
            } else {
                for (int j = 0; j < BKV; j++) Pb[r][j] = 0;
            }
            alphas[r] = alpha;
            lrow[r]   = l_r;
        }
        __syncthreads();

        // ---- O = alpha*O + P @ V ----
        {
            float av0 = alphas[wave*16 + quad*4 + 0];
            float av1 = alphas[wave*16 + quad*4 + 1];
            float av2 = alphas[wave*16 + quad*4 + 2];
            float av3 = alphas[wave*16 + quad*4 + 3];
            short8 pf = *(const short8*)&Pb[wave*16 + l15][quad*8];
            #pragma unroll
            for (int cv = 0; cv < 8; cv++) {
                oacc[cv][0] *= av0; oacc[cv][1] *= av1;
                oacc[cv][2] *= av2; oacc[cv][3] *= av3;
                short8 vf = *(const short8*)&Vt[cv*16 + l15][quad*8];
                oacc[cv] = __builtin_amdgcn_mfma_f32_16x16x32_bf16(pf, vf, oacc[cv], 0, 0, 0);
            }
        }
    }

    // ---- epilogue: O / l -> global bf16 (in-place into Q buffer is safe) ----
    __syncthreads();
    #pragma unroll
    for (int r = 0; r < 4; r++) {
        const int row = wave*16 + quad*4 + r;
        const float linv = 1.0f / lrow[row];
        u16* orow = Og + ((size_t)(b*T_ + q0 + row)*H_ + h)*HD_ + l15;
        #pragma unroll
        for (int cv = 0; cv < 8; cv++)
            orow[cv*16] = f2bf(oacc[cv][r] * linv);
    }
}

// ---------------------------------------------------------------------------
extern "C" void kernel_launch(void* const* d_in, const int* in_sizes, int n_in,
                              void* d_out, int out_size, void* d_ws, size_t ws_size,
                              hipStream_t stream)
{
    const float* x    = (const float*)d_in[0];   // [B,T,D]
    const float* Wq   = (const float*)d_in[1];   // [D, H*HD]
    const float* Wk   = (const float*)d_in[2];   // [D, KV*HD]
    const float* Wv   = (const float*)d_in[3];   // [D, KV*HD]
    const float* Wo   = (const float*)d_in[4];   // [H*HD, D]
    const float* qsc  = (const float*)d_in[5];   // [HD]
    const float* ksc  = (const float*)d_in[6];   // [HD]
    const float* cosT = (const float*)d_in[7];   // [T, HD]
    const float* sinT = (const float*)d_in[8];   // [T, HD]
    float* out = (float*)d_out;

    // Workspace carve (bf16, ~63 MB total)
    u16* xb    = (u16*)d_ws;                     // [BT, D]
    u16* Wqt   = xb  + (size_t)BT_*D_;           // [H*HD, D]
    u16* Wkt   = Wqt + (size_t)(H_*HD_)*D_;      // [KV*HD, D]
    u16* Wvt   = Wkt + (size_t)(KV_*HD_)*D_;     // [KV*HD, D]
    u16* Wot   = Wvt + (size_t)(KV_*HD_)*D_;     // [D, H*HD]
    u16* q_lin = Wot + (size_t)D_*(H_*HD_);      // [BT, H, HD]
    u16* k_lin = q_lin + (size_t)BT_*H_*HD_;     // [BT, KV, HD]
    u16* v_lin = k_lin + (size_t)BT_*KV_*HD_;    // [BT, KV, HD]

    // ---- convert x, transpose+convert weights ----
    cvt_f32_bf16_kernel<<<(BT_*D_)/1024, 256, 0, stream>>>(x, xb, BT_*D_);
    transpose_cvt_kernel<<<dim3((H_*HD_)/64,  D_/64), 256, 0, stream>>>(Wq, Wqt, D_, H_*HD_);
    transpose_cvt_kernel<<<dim3((KV_*HD_)/64, D_/64), 256, 0, stream>>>(Wk, Wkt, D_, KV_*HD_);
    transpose_cvt_kernel<<<dim3((KV_*HD_)/64, D_/64), 256, 0, stream>>>(Wv, Wvt, D_, KV_*HD_);
    transpose_cvt_kernel<<<dim3(D_/64, (H_*HD_)/64),  256, 0, stream>>>(Wo, Wot, H_*HD_, D_);

    // ---- q/k/v projections (MFMA) ----
    gemm_mfma_kernel<true><<<dim3((H_*HD_)/GBN,  BT_/GBM), 256, 0, stream>>>(
        xb, Wqt, q_lin, BT_, H_*HD_, D_);
    gemm_mfma_kernel<true><<<dim3((KV_*HD_)/GBN, BT_/GBM), 256, 0, stream>>>(
        xb, Wkt, k_lin, BT_, KV_*HD_, D_);
    gemm_mfma_kernel<true><<<dim3((KV_*HD_)/GBN, BT_/GBM), 256, 0, stream>>>(
        xb, Wvt, v_lin, BT_, KV_*HD_, D_);

    // ---- RMSNorm + RoPE in place ----
    rmsnorm_rope_kernel<<<BT_*H_,  HD_, 0, stream>>>(q_lin, qsc, cosT, sinT, H_);
    rmsnorm_rope_kernel<<<BT_*KV_, HD_, 0, stream>>>(k_lin, ksc, cosT, sinT, KV_);

    // ---- Flash attention (output in-place into q_lin) ----
    attn_mfma_kernel<<<dim3(T_/BQ, H_, B_), 256, 0, stream>>>(
        q_lin, k_lin, v_lin, q_lin);

    // ---- out = attn @ Wo (f32 out) ----
    gemm_mfma_kernel<false><<<dim3(D_/GBN, BT_/GBM), 256, 0, stream>>>(
        q_lin, Wot, out, BT_, D_, D_);
}

// Round 5
// 543.128 us; speedup vs baseline: 12.5534x; 1.7821x over previous
//
#include <hip/hip_runtime.h>
#include <hip/hip_bf16.h>

// Problem constants (from reference)
#define B_  2
#define T_  2048
#define D_  2048
#define H_  16
#define KV_ 4
#define HD_ 128
#define BT_ (B_*T_)          // 4096 token rows
#define KVP_ (2*KV_*HD_)     // 1024: row pitch of merged k|v projection output
static constexpr float EPS_ = 1e-6f;

typedef unsigned short u16;
typedef __attribute__((ext_vector_type(8))) short short8;          // 8 bf16 = 16 B
typedef __attribute__((ext_vector_type(4))) float f32x4;           // MFMA acc
typedef __attribute__((ext_vector_type(4))) unsigned short u16x4;  // 8 B

__device__ __forceinline__ u16 f2bf(float f){
    unsigned u = __float_as_uint(f);
    u += 0x7FFF + ((u >> 16) & 1);          // round-to-nearest-even
    return (u16)(u >> 16);
}
__device__ __forceinline__ float bf2f(u16 u){
    return __uint_as_float((unsigned)u << 16);
}

// Async global->LDS, 16 B per lane. LDS dest must be wave-uniform base + lane*16.
__device__ __forceinline__ void async_copy16(const void* g, void* l) {
    __builtin_amdgcn_global_load_lds(
        (const __attribute__((address_space(1))) unsigned int*)g,
        (__attribute__((address_space(3))) unsigned int*)l, 16, 0, 0);
}

// ---------------------------------------------------------------------------
// f32 -> bf16 elementwise convert (n % 4 == 0)
// ---------------------------------------------------------------------------
__global__ __launch_bounds__(256) void cvt_f32_bf16_kernel(
    const float* __restrict__ in, u16* __restrict__ out, int n)
{
    const int i = (blockIdx.x*256 + threadIdx.x)*4;
    if (i < n) {
        float4 v = *(const float4*)&in[i];
        u16x4 w = { f2bf(v.x), f2bf(v.y), f2bf(v.z), f2bf(v.w) };
        *(u16x4*)&out[i] = w;
    }
}

// ---------------------------------------------------------------------------
// Transpose + convert: in [R][C] f32  ->  out [C][R] bf16.  64x64 LDS tile.
// ---------------------------------------------------------------------------
__global__ __launch_bounds__(256) void transpose_cvt_kernel(
    const float* __restrict__ in, u16* __restrict__ out, int R, int C)
{
    __shared__ u16 tile[64][65];
    const int r0 = blockIdx.y*64, c0 = blockIdx.x*64;
    const int tr = threadIdx.x >> 4;          // 0..15
    const int tc = (threadIdx.x & 15) * 4;    // 0,4,..60
    #pragma unroll
    for (int i = 0; i < 4; i++) {
        const int r = tr + i*16;
        float4 v = *(const float4*)&in[(size_t)(r0 + r)*C + c0 + tc];
        tile[tc+0][r] = f2bf(v.x);
        tile[tc+1][r] = f2bf(v.y);
        tile[tc+2][r] = f2bf(v.z);
        tile[tc+3][r] = f2bf(v.w);
    }
    __syncthreads();
    #pragma unroll
    for (int i = 0; i < 4; i++) {
        const int c = tr + i*16;
        u16x4 w = { tile[c][tc+0], tile[c][tc+1], tile[c][tc+2], tile[c][tc+3] };
        *(u16x4*)&out[(size_t)(c0 + c)*R + r0 + tc] = w;
    }
}

// ---------------------------------------------------------------------------
// bf16 transpose of the V half of the merged kv buffer:
//   in:  kv[(b*T+t)*KVP_ + KV_*HD_ + kvh*HD_ + d]
//   out: vt[((b*KV_+kvh)*HD_ + d)*T_ + t]
// ---------------------------------------------------------------------------
__global__ __launch_bounds__(256) void transpose_v_kernel(
    const u16* __restrict__ kv, u16* __restrict__ vt)
{
    __shared__ u16 tile[64][65];
    const int t0 = blockIdx.x*64;
    const int d0 = blockIdx.y*64;              // 0 or 64
    const int bk = blockIdx.z;                 // b*KV_+kvh
    const int tr = threadIdx.x >> 4;           // 0..15
    const int tc = (threadIdx.x & 15) * 4;     // 0,4,..60
    #pragma unroll
    for (int i = 0; i < 4; i++) {
        const int t = t0 + tr + i*16;
        u16x4 v = *(const u16x4*)&kv[(size_t)((bk>>2)*T_ + t)*KVP_ + KV_*HD_
                                     + (bk&3)*HD_ + d0 + tc];
        tile[tc+0][tr+i*16] = v[0];
        tile[tc+1][tr+i*16] = v[1];
        tile[tc+2][tr+i*16] = v[2];
        tile[tc+3][tr+i*16] = v[3];
    }
    __syncthreads();
    #pragma unroll
    for (int i = 0; i < 4; i++) {
        const int d = tr + i*16;
        u16x4 w = { tile[d][tc+0], tile[d][tc+1], tile[d][tc+2], tile[d][tc+3] };
        *(u16x4*)&vt[((size_t)bk*HD_ + d0 + d)*T_ + t0 + tc] = w;
    }
}

// ---------------------------------------------------------------------------
// m97-style MFMA GEMM: C[M,N] = A[M,K] @ Bt[N,K]^T, bf16 in, f32 acc.
// (unchanged from round 4 — verified)
// ---------------------------------------------------------------------------
#define GBM 128
#define GBN 128
#define GBK 32

template<bool OUT_BF16>
__global__ __launch_bounds__(256) void gemm_mfma_kernel(
    const u16* __restrict__ A, const u16* __restrict__ Bt,
    void* __restrict__ C, int M, int N, int K)
{
    __shared__ __align__(16) u16 As[GBM][GBK];
    __shared__ __align__(16) u16 Bs[GBN][GBK];
    const int tid  = threadIdx.x;
    const int lane = tid & 63;
    const int wave = tid >> 6;
    const int l15  = lane & 15;
    const int quad = lane >> 4;
    const int wr   = (wave >> 1) * 64;
    const int wc   = (wave & 1) * 64;
    const size_t row0 = (size_t)blockIdx.y * GBM;
    const size_t col0 = (size_t)blockIdx.x * GBN;

    f32x4 acc[4][4];
    #pragma unroll
    for (int i = 0; i < 4; i++)
        #pragma unroll
        for (int j = 0; j < 4; j++)
            acc[i][j] = (f32x4){0.f,0.f,0.f,0.f};

    for (int k0 = 0; k0 < K; k0 += GBK) {
        #pragma unroll
        for (int c = 0; c < 2; c++) {
            const int e = (c*256 + tid) * 8;
            const int r = e >> 5, cc = e & 31;
            async_copy16(A  + (row0 + r)*K + k0 + cc, &As[r][cc]);
            async_copy16(Bt + (col0 + r)*K + k0 + cc, &Bs[r][cc]);
        }
        __syncthreads();

        short8 af[4], bf[4];
        #pragma unroll
        for (int i = 0; i < 4; i++)
            af[i] = *(const short8*)&As[wr + i*16 + l15][quad*8];
        #pragma unroll
        for (int j = 0; j < 4; j++)
            bf[j] = *(const short8*)&Bs[wc + j*16 + l15][quad*8];
        #pragma unroll
        for (int i = 0; i < 4; i++)
            #pragma unroll
            for (int j = 0; j < 4; j++)
                acc[i][j] = __builtin_amdgcn_mfma_f32_16x16x32_bf16(
                    af[i], bf[j], acc[i][j], 0, 0, 0);
        __syncthreads();
    }

    #pragma unroll
    for (int i = 0; i < 4; i++)
        #pragma unroll
        for (int r = 0; r < 4; r++) {
            const size_t row = row0 + wr + i*16 + quad*4 + r;
            #pragma unroll
            for (int j = 0; j < 4; j++) {
                const size_t col = col0 + wc + j*16 + l15;
                if (OUT_BF16) ((u16*)C)[row*N + col] = f2bf(acc[i][j][r]);
                else          ((float*)C)[row*N + col] = acc[i][j][r];
            }
        }
}

// ---------------------------------------------------------------------------
// Fused RMSNorm + RoPE, in place on bf16 rows with arbitrary token pitch.
// ---------------------------------------------------------------------------
__global__ __launch_bounds__(128) void rmsnorm_rope_kernel(
    u16* __restrict__ qk, const float* __restrict__ scale,
    const float* __restrict__ cosT, const float* __restrict__ sinT,
    int heads_per_token, int token_pitch)
{
    const int row   = blockIdx.x;
    const int d     = threadIdx.x;
    const int token = row / heads_per_token;
    const int hidx  = row % heads_per_token;
    const int t     = token % T_;
    u16* p = qk + (size_t)token*token_pitch + hidx*HD_;

    float v = bf2f(p[d]);
    __shared__ float red[HD_];
    __shared__ float xs[HD_];
    red[d] = v*v;
    __syncthreads();
    #pragma unroll
    for (int s = 64; s > 0; s >>= 1) {
        if (d < s) red[d] += red[d + s];
        __syncthreads();
    }
    const float rms = rsqrtf(red[0] * (1.0f/HD_) + EPS_);
    const float xn  = v * rms * scale[d];
    xs[d] = xn;
    __syncthreads();
    const float part = xs[d ^ 1];
    const float rot  = (d & 1) ? part : -part;
    p[d] = f2bf(xn*cosT[(size_t)t*HD_ + d] + rot*sinT[(size_t)t*HD_ + d]);
}

// ---------------------------------------------------------------------------
// Flash-style causal GQA attention v2.
//  - BQ=64 q-rows (one head) per block, 4 waves, wave = 16-row slab.
//  - BKV=64 keys per tile; 32 MFMA/wave/tile; 2 barriers/tile.
//  - In-register online softmax (shfl_xor width-16 row reductions).
//  - All LDS tiles chunk-major [k-chunk][row][8] -> 2-way-free ds_read_b128
//    and contiguous global_load_lds staging.
//  - V consumed pre-transposed from global (vt[(b,kvh)][d][t]).
// O may alias Q (block writes exactly the q-rows it alone reads).
// ---------------------------------------------------------------------------
#define BQ  64
#define BKV 64

__global__ __launch_bounds__(256) void attn_mfma2_kernel(
    const u16* __restrict__ Qg, const u16* __restrict__ Kg,
    const u16* __restrict__ Vtg, u16* __restrict__ Og)
{
    __shared__ __align__(16) u16 Qs[16][BQ][8];    // [k-chunk][q-row][8]  16 KB
    __shared__ __align__(16) u16 Ks[16][BKV][8];   // [k-chunk][key][8]    16 KB
    __shared__ __align__(16) u16 Vt[8][HD_][8];    // [key-chunk][d][8]    16 KB
    __shared__ __align__(16) u16 Pb[4][8][16][8];  // [wave][key-chunk][row][8] 8 KB

    const int qt   = (gridDim.x - 1) - blockIdx.x;   // heavy (long-causal) first
    const int h    = blockIdx.y;
    const int b    = blockIdx.z;
    const int q0   = qt * BQ;
    const int kvh  = h >> 2;                          // H_/KV_ = 4
    const int tid  = threadIdx.x;
    const int lane = tid & 63;
    const int wave = tid >> 6;
    const int l15  = lane & 15;
    const int quad = lane >> 4;
    const float SCALE = 0.08838834764831845f;        // 1/sqrt(128)

    // ---- stage Q tile once (async, contiguous) ----
    #pragma unroll
    for (int it = 0; it < 4; it++) {
        const int n   = it*256 + tid;
        const int cc  = n >> 6;
        const int row = n & 63;
        async_copy16(Qg + ((size_t)(b*T_ + q0 + row)*H_ + h)*HD_ + cc*8,
                     &Qs[cc][row][0]);
    }

    float m_r[4] = {-INFINITY,-INFINITY,-INFINITY,-INFINITY};
    float l_r[4] = {0.f,0.f,0.f,0.f};
    f32x4 oacc[8];
    #pragma unroll
    for (int cv = 0; cv < 8; cv++) oacc[cv] = (f32x4){0.f,0.f,0.f,0.f};

    const int ntiles = qt + 1;
    for (int t = 0; t < ntiles; t++) {
        const int k0 = t * BKV;
        __syncthreads();        // all waves done reading prev K/V tiles

        // ---- stage K tile [16cc][64key] ----
        #pragma unroll
        for (int it = 0; it < 4; it++) {
            const int n   = it*256 + tid;
            const int cc  = n >> 6;
            const int key = n & 63;
            async_copy16(Kg + (size_t)(b*T_ + k0 + key)*KVP_ + kvh*HD_ + cc*8,
                         &Ks[cc][key][0]);
        }
        // ---- stage V^T tile [8cc][128d] ----
        #pragma unroll
        for (int it = 0; it < 4; it++) {
            const int n  = it*256 + tid;
            const int cc = n >> 7;
            const int d  = n & 127;
            async_copy16(Vtg + ((size_t)(b*KV_ + kvh)*HD_ + d)*T_ + k0 + cc*8,
                         &Vt[cc][d][0]);
        }
        __syncthreads();        // drains vmcnt(0): staged data visible

        // ---- S = Q @ K^T : wave slab (16 rows) x 64 keys ----
        f32x4 s[4];
        #pragma unroll
        for (int c = 0; c < 4; c++) s[c] = (f32x4){0.f,0.f,0.f,0.f};
        #pragma unroll
        for (int kt = 0; kt < 4; kt++) {
            short8 a = *(const short8*)&Qs[kt*4 + quad][wave*16 + l15][0];
            #pragma unroll
            for (int c = 0; c < 4; c++) {
                short8 bf = *(const short8*)&Ks[kt*4 + quad][c*16 + l15][0];
                s[c] = __builtin_amdgcn_mfma_f32_16x16x32_bf16(a, bf, s[c], 0, 0, 0);
            }
        }

        // ---- in-register online softmax (C-layout: row=quad*4+r, col=c*16+l15) ----
        const int qrow0 = q0 + wave*16 + quad*4;
        float alpha[4];
        #pragma unroll
        for (int r = 0; r < 4; r++) {
            #pragma unroll
            for (int c = 0; c < 4; c++) {
                const int key = k0 + c*16 + l15;
                s[c][r] = (key <= qrow0 + r) ? s[c][r]*SCALE : -1e30f;
            }
            float mloc = fmaxf(fmaxf(s[0][r], s[1][r]), fmaxf(s[2][r], s[3][r]));
            #pragma unroll
            for (int off = 1; off < 16; off <<= 1)
                mloc = fmaxf(mloc, __shfl_xor(mloc, off, 16));
            const float mn = fmaxf(m_r[r], mloc);
            alpha[r] = __expf(m_r[r] - mn);
            m_r[r] = mn;
            float lad = 0.f;
            #pragma unroll
            for (int c = 0; c < 4; c++) {
                const float p = __expf(s[c][r] - mn);
                s[c][r] = p;
                lad += p;
            }
            #pragma unroll
            for (int off = 1; off < 16; off <<= 1)
                lad += __shfl_xor(lad, off, 16);
            l_r[r] = alpha[r]*l_r[r] + lad;
        }

        // ---- P -> wave-private LDS (A-operand layout), no barrier needed ----
        #pragma unroll
        for (int r = 0; r < 4; r++)
            #pragma unroll
            for (int c = 0; c < 4; c++)
                Pb[wave][c*2 + (l15 >> 3)][quad*4 + r][l15 & 7] = f2bf(s[c][r]);

        // ---- rescale O, then O += P @ V ----
        #pragma unroll
        for (int cv = 0; cv < 8; cv++)
            #pragma unroll
            for (int r = 0; r < 4; r++)
                oacc[cv][r] *= alpha[r];

        #pragma unroll
        for (int kt2 = 0; kt2 < 2; kt2++) {
            short8 a = *(const short8*)&Pb[wave][kt2*4 + quad][l15][0];
            #pragma unroll
            for (int cv = 0; cv < 8; cv++) {
                short8 vf = *(const short8*)&Vt[kt2*4 + quad][cv*16 + l15][0];
                oacc[cv] = __builtin_amdgcn_mfma_f32_16x16x32_bf16(a, vf, oacc[cv], 0, 0, 0);
            }
        }
    }

    // ---- epilogue: O / l -> global bf16 (in-place into Q buffer is safe) ----
    #pragma unroll
    for (int r = 0; r < 4; r++) {
        const float linv = 1.0f / l_r[r];
        u16* orow = Og + ((size_t)(b*T_ + q0 + wave*16 + quad*4 + r)*H_ + h)*HD_ + l15;
        #pragma unroll
        for (int cv = 0; cv < 8; cv++)
            orow[cv*16] = f2bf(oacc[cv][r] * linv);
    }
}

// ---------------------------------------------------------------------------
extern "C" void kernel_launch(void* const* d_in, const int* in_sizes, int n_in,
                              void* d_out, int out_size, void* d_ws, size_t ws_size,
                              hipStream_t stream)
{
    const float* x    = (const float*)d_in[0];   // [B,T,D]
    const float* Wq   = (const float*)d_in[1];   // [D, H*HD]
    const float* Wk   = (const float*)d_in[2];   // [D, KV*HD]
    const float* Wv   = (const float*)d_in[3];   // [D, KV*HD]
    const float* Wo   = (const float*)d_in[4];   // [H*HD, D]
    const float* qsc  = (const float*)d_in[5];   // [HD]
    const float* ksc  = (const float*)d_in[6];   // [HD]
    const float* cosT = (const float*)d_in[7];   // [T, HD]
    const float* sinT = (const float*)d_in[8];   // [T, HD]
    float* out = (float*)d_out;

    // Workspace carve (bf16, ~67 MB total)
    u16* xb     = (u16*)d_ws;                     // [BT, D]
    u16* Wqt    = xb     + (size_t)BT_*D_;        // [2048, D]
    u16* Wkvt   = Wqt    + (size_t)(H_*HD_)*D_;   // [1024, D] (Wk^T rows then Wv^T rows)
    u16* Wot    = Wkvt   + (size_t)KVP_*D_;       // [D, 2048]
    u16* q_lin  = Wot    + (size_t)D_*(H_*HD_);   // [BT, H, HD]
    u16* kv_lin = q_lin  + (size_t)BT_*H_*HD_;    // [BT, 1024] = k|v merged
    u16* vtg    = kv_lin + (size_t)BT_*KVP_;      // [B*KV, HD, T] = V^T
    u16* Wvt    = Wkvt   + (size_t)(KV_*HD_)*D_;  // second half of Wkvt

    // ---- convert x, transpose+convert weights ----
    cvt_f32_bf16_kernel<<<(BT_*D_)/1024, 256, 0, stream>>>(x, xb, BT_*D_);
    transpose_cvt_kernel<<<dim3((H_*HD_)/64,  D_/64), 256, 0, stream>>>(Wq, Wqt, D_, H_*HD_);
    transpose_cvt_kernel<<<dim3((KV_*HD_)/64, D_/64), 256, 0, stream>>>(Wk, Wkvt, D_, KV_*HD_);
    transpose_cvt_kernel<<<dim3((KV_*HD_)/64, D_/64), 256, 0, stream>>>(Wv, Wvt, D_, KV_*HD_);
    transpose_cvt_kernel<<<dim3(D_/64, (H_*HD_)/64),  256, 0, stream>>>(Wo, Wot, H_*HD_, D_);

    // ---- projections: q (N=2048) and merged k|v (N=1024) ----
    gemm_mfma_kernel<true><<<dim3((H_*HD_)/GBN, BT_/GBM), 256, 0, stream>>>(
        xb, Wqt, q_lin, BT_, H_*HD_, D_);
    gemm_mfma_kernel<true><<<dim3(KVP_/GBN, BT_/GBM), 256, 0, stream>>>(
        xb, Wkvt, kv_lin, BT_, KVP_, D_);

    // ---- RMSNorm + RoPE in place (q; k half of kv) ----
    rmsnorm_rope_kernel<<<BT_*H_,  HD_, 0, stream>>>(q_lin, qsc, cosT, sinT, H_, H_*HD_);
    rmsnorm_rope_kernel<<<BT_*KV_, HD_, 0, stream>>>(kv_lin, ksc, cosT, sinT, KV_, KVP_);

    // ---- V^T into global [b*KV][d][t] ----
    transpose_v_kernel<<<dim3(T_/64, HD_/64, B_*KV_), 256, 0, stream>>>(kv_lin, vtg);

    // ---- Flash attention v2 (output in-place into q_lin) ----
    attn_mfma2_kernel<<<dim3(T_/BQ, H_, B_), 256, 0, stream>>>(
        q_lin, kv_lin, vtg, q_lin);

    // ---- out = attn @ Wo (f32 out) ----
    gemm_mfma_kernel<false><<<dim3(D_/GBN, BT_/GBM), 256, 0, stream>>>(
        q_lin, Wot, out, BT_, D_, D_);
}